// Round 14
// baseline (182.907 us; speedup 1.0000x reference)
//
#include <hip/hip_runtime.h>

// Problem constants (fixed by setup_inputs)
#define NTOK   2048
#define DIM    256
#define NH     8
#define CH     32
#define QB     8                      // queries per attn block (K2)
#define TOPK_K 16
#define SCALE  0.17677669529663687f   // 32^-0.5
#define LN_EPS 1e-5f

// pbuf: [head][q (8)][key-in-tile (256 + pad)]
#define PBL    260
#define PBH    (QB * PBL)             // 2080 floats per head
#define PSCALE 16384.f                // p -> f16 scaling (avoid denormal flush)
#define RPSCALE (1.f / 16384.f)

typedef _Float16 h16;
typedef _Float16 h16x8 __attribute__((ext_vector_type(8)));   // 4 VGPRs: MFMA A/B frag
typedef float    f32x4 __attribute__((ext_vector_type(4)));   // MFMA C/D frag

#define MFMA16(a, b, c) __builtin_amdgcn_mfma_f32_16x16x32_f16((a), (b), (c), 0, 0, 0)

// Fragment layouts (R7/R8-proven):
//   KF[w][kg(128)][hl(2)][l(64)][j(8)]: (l,j) = K[kg*16+(l&15)][w*32+8*(l>>4)+j]
//   VF[w][kb(64)][h(2)][l(64)][j(8)] : (l,j) = V[kb*32+8*(l>>4)+j][w*32+h*16+(l&15)]
//   WF/WP[cg][ks(8)][hl(2)][l(64)][j(8)]: (l,j) = W[ks*32+8*(l>>4)+j][cg*16+(l&15)]

// block-wide sum, NT threads (multiple of 64); red[] holds NT/64 floats
template<int NT>
__device__ __forceinline__ float block_sum(float v, float* red){
  #pragma unroll
  for (int off = 32; off > 0; off >>= 1) v += __shfl_xor(v, off, 64);
  const int t = threadIdx.x;
  if ((t & 63) == 0) red[t >> 6] = v;
  __syncthreads();
  float s = 0.f;
  #pragma unroll
  for (int w = 0; w < NT/64; w++) s += red[w];
  __syncthreads();
  return s;
}

// ---------------- K0: merged weight reorder -> fragment layout (one launch) ----------------
__global__ __launch_bounds__(256) void reorder_w_kernel(
    const float* __restrict__ src_qkv, const float* __restrict__ src_proj,
    h16* __restrict__ WF, h16* __restrict__ WP)
{
  const int b = blockIdx.x;
  const float* src; h16* dst; int ld, pair;
  if (b < 96){ src = src_qkv;  dst = WF; ld = 768; pair = b * 4 + (threadIdx.x >> 6); }
  else       { src = src_proj; dst = WP; ld = 256; pair = (b - 96) * 4 + (threadIdx.x >> 6); }
  const int l  = threadIdx.x & 63;
  const int cg = pair >> 3, ks = pair & 7;
  h16x8 hi8, lo8;
  #pragma unroll
  for (int j = 0; j < 8; j++){
    const float v = src[(size_t)(ks * 32 + (l >> 4) * 8 + j) * ld + cg * 16 + (l & 15)];
    const h16 h = (h16)v;
    hi8[j] = h;
    lo8[j] = (h16)(v - (float)h);
  }
  *(h16x8*)&dst[(size_t)((cg * 8 + ks) * 2 + 0) * 512 + l * 8] = hi8;
  *(h16x8*)&dst[(size_t)((cg * 8 + ks) * 2 + 1) * 512 + l * 8] = lo8;
}

// ---------------- K1: LN1 + MFMA x@w_qkv -> Q, KF, VF, V (R9-proven verbatim) ----------------
__global__ __launch_bounds__(1024) void ln_qkv_kernel(
    const float* __restrict__ point,
    const h16*   __restrict__ WF,
    const float* __restrict__ c1,
    const float* __restrict__ c2,
    float* __restrict__ Q,
    h16*   __restrict__ KF,
    h16*   __restrict__ VF,
    float* __restrict__ V)
{
  __shared__ float xs[16][261];
  __shared__ float garr[256], barr[256];
  __shared__ float red[16];
  const int t  = threadIdx.x;
  const int wv = t >> 6;
  const int l  = t & 63;
  const int r  = l & 15;
  const int g  = l >> 4;
  const int tg = blockIdx.x >> 1;
  const int ch = blockIdx.x & 1;
  const int l0 = tg * 16;

  const float a1 = (t < 256) ? c1[t] : 0.f;
  const float a2 = (t < 256) ? c2[t] : 0.f;
  const float s1 = block_sum<1024>(fabsf(a1), red);
  const float s2 = block_sum<1024>(fabsf(a2), red);
  if (t < 256){ garr[t] = (s1 > s2) ? a1 : a2; barr[t] = (s1 > s2) ? a2 : a1; }
  __syncthreads();

  { // LN: wave wv -> token row l0+wv
    const float4 x = *(const float4*)&point[(size_t)(l0 + wv) * DIM + 4 * l];
    float s = x.x + x.y + x.z + x.w;
    #pragma unroll
    for (int off = 1; off < 64; off <<= 1) s += __shfl_xor(s, off, 64);
    const float mu = s * (1.f / DIM);
    const float d0 = x.x - mu, d1 = x.y - mu, d2 = x.z - mu, d3 = x.w - mu;
    float ss = d0 * d0 + d1 * d1 + d2 * d2 + d3 * d3;
    #pragma unroll
    for (int off = 1; off < 64; off <<= 1) ss += __shfl_xor(ss, off, 64);
    const float rsd = rsqrtf(ss * (1.f / DIM) + LN_EPS);
    xs[wv][4 * l + 0] = d0 * rsd * garr[4 * l + 0] + barr[4 * l + 0];
    xs[wv][4 * l + 1] = d1 * rsd * garr[4 * l + 1] + barr[4 * l + 1];
    xs[wv][4 * l + 2] = d2 * rsd * garr[4 * l + 2] + barr[4 * l + 2];
    xs[wv][4 * l + 3] = d3 * rsd * garr[4 * l + 3] + barr[4 * l + 3];
  }
  __syncthreads();

  // A fragments: row = token r, k = ks*32 + 8g + j; f16 hi/lo split
  h16x8 ah[8], al[8];
  #pragma unroll
  for (int ks = 0; ks < 8; ks++){
    #pragma unroll
    for (int j = 0; j < 8; j++){
      const float v = xs[r][ks * 32 + 8 * g + j];
      const h16 hi = (h16)v;
      ah[ks][j] = hi;
      al[ks][j] = (h16)(v - (float)hi);
    }
  }

  const int kgb = tg;   // this block's 16 tokens = KF key-group tg
  #pragma unroll
  for (int cgi = 0; cgi < 2; cgi++){
    if (cgi == 1 && wv >= 8) break;
    const int cg = ch * 24 + (cgi == 0 ? wv : 16 + wv);
    f32x4 acc = {0.f, 0.f, 0.f, 0.f};
    const h16* wf = WF + (size_t)cg * 8192 + (size_t)l * 8;
    #pragma unroll
    for (int ks = 0; ks < 8; ks++){
      const h16x8 bh = *(const h16x8*)(wf + ks * 1024);
      const h16x8 bl = *(const h16x8*)(wf + ks * 1024 + 512);
      acc = MFMA16(ah[ks], bh, acc);
      acc = MFMA16(al[ks], bh, acc);
      acc = MFMA16(ah[ks], bl, acc);
    }
    const int typ = cg >> 4;             // 0=Q, 1=K, 2=V
    const int c0  = (cg & 15) * 16 + r;  // column within its matrix
    #pragma unroll
    for (int q4 = 0; q4 < 4; q4++){
      const int tok = 4 * g + q4;
      if (typ == 0){
        Q[(size_t)(l0 + tok) * DIM + c0] = acc[q4];
      } else if (typ == 1){
        const int wh = c0 >> 5, gp = (c0 & 31) >> 3, jj = c0 & 7;
        const float kv = acc[q4];
        const h16 kh2 = (h16)kv;
        const size_t kidx = (size_t)(wh * 128 + kgb) * 1024
                          + (size_t)(gp * 16 + tok) * 8 + jj;
        KF[kidx]       = kh2;
        KF[kidx + 512] = (h16)(kv - (float)kh2);
      } else {
        V[(size_t)(l0 + tok) * DIM + c0] = acc[q4];
        const int wh = c0 >> 5, hh = (c0 & 31) >> 4, cp = c0 & 15;
        const int key = l0 + tok;
        const int kb = key >> 5, krem = key & 31, gpp = krem >> 3, jpp = krem & 7;
        VF[(size_t)((wh * 64 + kb) * 2 + hh) * 512
           + (size_t)(gpp * 16 + cp) * 8 + jpp] = (h16)acc[q4];
      }
    }
  }
}

// ---------------- Zk: softmax denominators (R9-proven verbatim) ----------------
__global__ __launch_bounds__(1024) void z_kernel(
    const float* __restrict__ Q,
    const h16*   __restrict__ KF,
    float*       __restrict__ Zp)     // [4][NH][NTOK]
{
  const int t  = threadIdx.x;
  const int wv = t >> 6;
  const int w  = wv & 7;
  const int sh = wv >> 3;
  const int l  = t & 63;
  const int r  = l & 15;
  const int g  = l >> 4;
  const int tg = blockIdx.x >> 1;
  const int hb = blockIdx.x & 1;

  h16x8 qh, ql;
  {
    const float* qp = &Q[(size_t)(tg * 16 + r) * DIM + w * CH + 8 * g];
    const float4 q0 = *(const float4*)qp;
    const float4 q1 = *(const float4*)(qp + 4);
    const float qv[8] = {q0.x, q0.y, q0.z, q0.w, q1.x, q1.y, q1.z, q1.w};
    #pragma unroll
    for (int j = 0; j < 8; j++){
      const float s = qv[j] * SCALE;
      const h16 hi = (h16)s;
      qh[j] = hi;
      ql[j] = (h16)(s - (float)hi);
    }
  }

  const h16* kf = KF + (size_t)(w * 128 + hb * 64 + sh * 32) * 1024 + (size_t)l * 8;
  float zs[4] = {0.f, 0.f, 0.f, 0.f};
  #pragma unroll 2
  for (int kgi = 0; kgi < 32; kgi++){
    const h16x8 bh = *(const h16x8*)(kf + (size_t)kgi * 1024);
    const h16x8 bl = *(const h16x8*)(kf + (size_t)kgi * 1024 + 512);
    f32x4 d = {0.f, 0.f, 0.f, 0.f};
    d = MFMA16(qh, bh, d);
    d = MFMA16(ql, bh, d);
    d = MFMA16(qh, bl, d);
    #pragma unroll
    for (int q4 = 0; q4 < 4; q4++) zs[q4] += __expf(d[q4]);
  }
  #pragma unroll
  for (int q4 = 0; q4 < 4; q4++){
    #pragma unroll
    for (int off = 1; off < 16; off <<= 1) zs[q4] += __shfl_xor(zs[q4], off, 64);
  }
  if (r == 0){
    #pragma unroll
    for (int q4 = 0; q4 < 4; q4++)
      Zp[(size_t)((hb * 2 + sh) * NH + w) * NTOK + tg * 16 + 4 * g + q4] = zs[q4];
  }
}

// ---------------- K2: single-sweep MFMA attention + A_mean + top-k ----------------
// ROUND-14 CHANGE (K2 only): the barrier between scores and PV is REMOVED.
// PV reads pbuf[w][r<8][hf*128+..] — written entirely by the SAME wave in the
// score phase (same-wave DS ordering; R4's e-bounce proved this pattern).
// Only A_mean reads cross-head data -> barriers bracket just A_mean: 1 convoy
// pair per tile instead of 2 phases locked. All 4 PV frag pairs issue at tile
// start (deeper T14, legal now that no barrier splits the phase). A_mean uses
// all 1024 threads (float2). T5 setprio around MFMA clusters (waves now run
// staggered -> scheduler has something to arbitrate).
__global__ __launch_bounds__(1024) __attribute__((amdgpu_waves_per_eu(4)))
void attn_fused_kernel(
    const float* Q,                   // [NTOK][DIM] f32 (aliases msg! no restrict)
    const h16*   __restrict__ KF,
    const h16*   __restrict__ VF,
    const float* __restrict__ Zp,     // [4][NH][NTOK] partial Z
    float*       msg,                 // = Q buffer; block-local overlay
    float*       __restrict__ out_idx)
{
  __shared__ float pbuf[NH * PBH];          // 66560 B
  __shared__ float am[QB][NTOK];            // 65536 B
  __shared__ float msg_s[2][QB][DIM + 4];   // 16640 B
  __shared__ float zbuf[NH * QB];           // 256 B: summed Z per (head, q)

  const int t  = threadIdx.x;
  const int wv = t >> 6;
  const int w  = wv & 7;
  const int hf = wv >> 3;
  const int l  = t & 63;
  const int r  = l & 15;
  const int g  = l >> 4;
  const int l0 = blockIdx.x * QB;

  // ---- Q fragments (A operand), pre-scaled, f16 hi/lo split; rows 8..15 zero
  h16x8 qh, ql;
  #pragma unroll
  for (int j = 0; j < 8; j++){ qh[j] = (h16)0.f; ql[j] = (h16)0.f; }
  if (r < QB){
    const float* qp = &Q[(size_t)(l0 + r) * DIM + w * CH + 8 * g];
    const float4 q0 = *(const float4*)qp;
    const float4 q1 = *(const float4*)(qp + 4);
    const float qv[8] = {q0.x, q0.y, q0.z, q0.w, q1.x, q1.y, q1.z, q1.w};
    #pragma unroll
    for (int j = 0; j < 8; j++){
      const float s = qv[j] * SCALE;
      const h16 hi = (h16)s;
      qh[j] = hi;
      ql[j] = (h16)(s - (float)hi);
    }
  }

  // stage Z sums: thread t<64 -> (head t>>3, q t&7)
  if (t < 64){
    const int h = t >> 3, q = t & 7;
    float z = 0.f;
    #pragma unroll
    for (int p = 0; p < 4; p++) z += Zp[(size_t)(p * NH + h) * NTOK + l0 + q];
    zbuf[t] = z;
  }
  __syncthreads();
  float rZ[4];
  #pragma unroll
  for (int q4 = 0; q4 < 4; q4++){
    const int row = 4 * g + q4;
    rZ[q4] = (g < 2) ? 1.f / zbuf[w * QB + row] : 0.f;
  }

  // per-lane fragment bases
  const h16* kfw = KF + (size_t)(w * 128) * 1024 + (size_t)l * 8;
  const h16* vfw = VF + (size_t)(w * 64) * 1024 + (size_t)l * 8;

  f32x4 macc[2];
  #pragma unroll
  for (int dg = 0; dg < 2; dg++) macc[dg] = (f32x4){0.f, 0.f, 0.f, 0.f};

  for (int ti = 0; ti < 8; ti++){
    const int s0 = ti * 256;
    const h16* vft = vfw + (size_t)((ti * 8 + hf * 4) * 2) * 512;

    // T14 issue-early: ALL 4 PV B-frag pairs (8 KB/wave in flight over scores)
    h16x8 pva[4], pvb[4];
    #pragma unroll
    for (int st = 0; st < 4; st++){
      pva[st] = *(const h16x8*)(vft + st * 1024);
      pvb[st] = *(const h16x8*)(vft + st * 1024 + 512);
    }

    // (a) scores -> normalized p for this wave's 128 keys of the tile
    {
      const h16* kft = kfw + (size_t)(ti * 16 + hf * 8) * 1024;
      #pragma unroll 2
      for (int kgi = 0; kgi < 8; kgi++){
        const h16x8 bh = *(const h16x8*)(kft + (size_t)kgi * 1024);
        const h16x8 bl = *(const h16x8*)(kft + (size_t)kgi * 1024 + 512);
        f32x4 d = {0.f, 0.f, 0.f, 0.f};
        __builtin_amdgcn_s_setprio(1);
        d = MFMA16(qh, bh, d);
        d = MFMA16(ql, bh, d);
        d = MFMA16(qh, bl, d);
        __builtin_amdgcn_s_setprio(0);
        if (g < 2){
          const int kbr = hf * 128 + kgi * 16 + r;
          pbuf[w * PBH + (4 * g + 0) * PBL + kbr] = __expf(d[0]) * rZ[0];
          pbuf[w * PBH + (4 * g + 1) * PBL + kbr] = __expf(d[1]) * rZ[1];
          pbuf[w * PBH + (4 * g + 2) * PBL + kbr] = __expf(d[2]) * rZ[2];
          pbuf[w * PBH + (4 * g + 3) * PBL + kbr] = __expf(d[3]) * rZ[3];
        }
      }
    }

    // (b) PV immediately — NO barrier: wave w reads only the pbuf region it
    // itself wrote this tile (same-wave DS ordering guarantees visibility).
    #pragma unroll
    for (int st = 0; st < 4; st++){
      h16x8 pa;
      #pragma unroll
      for (int j = 0; j < 8; j++) pa[j] = (h16)0.f;
      if (r < QB){
        const float* pp = &pbuf[w * PBH + r * PBL + hf * 128 + st * 32 + 8 * g];
        const float4 p0 = *(const float4*)pp;
        const float4 p1 = *(const float4*)(pp + 4);
        pa[0] = (h16)(p0.x * PSCALE); pa[1] = (h16)(p0.y * PSCALE);
        pa[2] = (h16)(p0.z * PSCALE); pa[3] = (h16)(p0.w * PSCALE);
        pa[4] = (h16)(p1.x * PSCALE); pa[5] = (h16)(p1.y * PSCALE);
        pa[6] = (h16)(p1.z * PSCALE); pa[7] = (h16)(p1.w * PSCALE);
      }
      __builtin_amdgcn_s_setprio(1);
      macc[0] = MFMA16(pa, pva[st], macc[0]);
      macc[1] = MFMA16(pa, pvb[st], macc[1]);
      __builtin_amdgcn_s_setprio(0);
    }
    __syncthreads();   // all heads' p visible for the cross-head A_mean

    // (c) A_mean: 2048 cells, all 1024 threads, float2 each
    {
      const int q   = t >> 7;
      const int k2c = (t & 127) * 2;
      float sx = 0.f, sy = 0.f;
      #pragma unroll
      for (int hh = 0; hh < 8; hh++){
        const float2 v = *(const float2*)&pbuf[hh * PBH + q * PBL + k2c];
        sx += v.x; sy += v.y;
      }
      *(float2*)&am[q][s0 + k2c] = make_float2(sx * 0.125f, sy * 0.125f);
    }
    __syncthreads();   // protect pbuf before next tile's writes
  }

  // ---- epilogue: msg partials to LDS
  if (g < 2){
    #pragma unroll
    for (int dg = 0; dg < 2; dg++)
      #pragma unroll
      for (int q4 = 0; q4 < 4; q4++)
        msg_s[hf][4 * g + q4][w * CH + dg * 16 + r] = macc[dg][q4] * RPSCALE;
  }
  __syncthreads();

  if (wv < QB){
    // top-k: wave wv owns query row wv
    for (int it = 0; it < TOPK_K; it++){
      float bv = -1e30f; int bi = 0x7fffffff;
      #pragma unroll
      for (int b = 0; b < NTOK / 64; b++){
        const int idx = b * 64 + l;
        const float v = am[wv][idx];
        if (v > bv || (v == bv && idx < bi)){ bv = v; bi = idx; }
      }
      #pragma unroll
      for (int off = 1; off < 64; off <<= 1){
        const float ov = __shfl_xor(bv, off, 64);
        const int   oi = __shfl_xor(bi, off, 64);
        if (ov > bv || (ov == bv && oi < bi)){ bv = ov; bi = oi; }
      }
      if (l == 0){
        out_idx[(l0 + wv) * TOPK_K + it] = (float)bi;
        am[wv][bi] = -1e30f;
      }
    }
  } else {
    // waves 8..15: combine halves, write msg (overlays Q: block-local rows only)
    const int t2 = t - 512;
    #pragma unroll
    for (int k2 = 0; k2 < 4; k2++){
      const int cell = t2 + 512 * k2;
      const int q = cell >> 8, dcol = cell & 255;
      msg[(size_t)(l0 + q) * DIM + dcol] = msg_s[0][q][dcol] + msg_s[1][q][dcol];
    }
  }
}

// ---------------- K3: MFMA msg@w_proj + b + V residual + LN2 -> out (R9-proven) ----------------
__global__ __launch_bounds__(1024) void proj_ln_kernel(
    const float* __restrict__ msg,
    const float* __restrict__ V,
    const h16*   __restrict__ WP,
    const float* __restrict__ b_proj,
    const float* __restrict__ c1,
    const float* __restrict__ c2,
    float* __restrict__ out)
{
  __shared__ float xs[16][261];
  __shared__ float ms2[16][261];
  __shared__ float garr[256], barr[256], bparr[256];
  __shared__ float red[16];
  const int t  = threadIdx.x;
  const int wv = t >> 6;
  const int l  = t & 63;
  const int r  = l & 15;
  const int g  = l >> 4;
  const int l0 = blockIdx.x * 16;

  const float a1 = (t < 256) ? c1[t] : 0.f;
  const float a2 = (t < 256) ? c2[t] : 0.f;
  const float s1 = block_sum<1024>(fabsf(a1), red);
  const float s2 = block_sum<1024>(fabsf(a2), red);
  if (t < 256){
    garr[t]  = (s1 > s2) ? a1 : a2;
    barr[t]  = (s1 > s2) ? a2 : a1;
    bparr[t] = b_proj[t];
  }

  {
    const float4 x = *(const float4*)&msg[(size_t)(l0 + wv) * DIM + 4 * l];
    xs[wv][4 * l + 0] = x.x; xs[wv][4 * l + 1] = x.y;
    xs[wv][4 * l + 2] = x.z; xs[wv][4 * l + 3] = x.w;
  }
  __syncthreads();

  h16x8 ah[8], al[8];
  #pragma unroll
  for (int ks = 0; ks < 8; ks++){
    #pragma unroll
    for (int j = 0; j < 8; j++){
      const float v = xs[r][ks * 32 + 8 * g + j];
      const h16 hi = (h16)v;
      ah[ks][j] = hi;
      al[ks][j] = (h16)(v - (float)hi);
    }
  }

  f32x4 acc = {0.f, 0.f, 0.f, 0.f};
  {
    const h16* wp = WP + (size_t)wv * 8192 + (size_t)l * 8;
    #pragma unroll
    for (int ks = 0; ks < 8; ks++){
      const h16x8 bh = *(const h16x8*)(wp + ks * 1024);
      const h16x8 bl = *(const h16x8*)(wp + ks * 1024 + 512);
      acc = MFMA16(ah[ks], bh, acc);
      acc = MFMA16(al[ks], bh, acc);
      acc = MFMA16(ah[ks], bl, acc);
    }
  }

  const int dc = wv * 16 + r;
  #pragma unroll
  for (int q4 = 0; q4 < 4; q4++){
    const int tok = 4 * g + q4;
    ms2[tok][dc] = acc[q4] + bparr[dc] + V[(size_t)(l0 + tok) * DIM + dc];
  }
  __syncthreads();

  {
    const float x0 = ms2[wv][4 * l + 0], x1 = ms2[wv][4 * l + 1];
    const float x2 = ms2[wv][4 * l + 2], x3 = ms2[wv][4 * l + 3];
    float s = x0 + x1 + x2 + x3;
    #pragma unroll
    for (int off = 1; off < 64; off <<= 1) s += __shfl_xor(s, off, 64);
    const float mu = s * (1.f / DIM);
    const float d0 = x0 - mu, d1 = x1 - mu, d2 = x2 - mu, d3 = x3 - mu;
    float ss = d0 * d0 + d1 * d1 + d2 * d2 + d3 * d3;
    #pragma unroll
    for (int off = 1; off < 64; off <<= 1) ss += __shfl_xor(ss, off, 64);
    const float rsd = rsqrtf(ss * (1.f / DIM) + LN_EPS);
    float4 o;
    o.x = d0 * rsd * garr[4 * l + 0] + barr[4 * l + 0];
    o.y = d1 * rsd * garr[4 * l + 1] + barr[4 * l + 1];
    o.z = d2 * rsd * garr[4 * l + 2] + barr[4 * l + 2];
    o.w = d3 * rsd * garr[4 * l + 3] + barr[4 * l + 3];
    *(float4*)&out[(size_t)(l0 + wv) * DIM + 4 * l] = o;
  }
}

extern "C" void kernel_launch(void* const* d_in, const int* in_sizes, int n_in,
                              void* d_out, int out_size, void* d_ws, size_t ws_size,
                              hipStream_t stream) {
  const float* point  = nullptr;
  const float* w_qkv  = nullptr;
  const float* w_proj = nullptr;
  const float* v256[5] = {nullptr, nullptr, nullptr, nullptr, nullptr};
  int n256 = 0;
  for (int i = 0; i < n_in; i++){
    const int sz = in_sizes[i];
    if      (sz == NTOK * DIM)      point  = (const float*)d_in[i];
    else if (sz == DIM * 3 * DIM)   w_qkv  = (const float*)d_in[i];
    else if (sz == DIM * DIM)       w_proj = (const float*)d_in[i];
    else if (sz == DIM && n256 < 5) v256[n256++] = (const float*)d_in[i];
  }
  const float* b_proj = v256[0];
  const float* n1a    = v256[1];
  const float* n1c    = v256[2];
  const float* n2a    = v256[3];
  const float* n2c    = v256[4];

  // Output buffer f32: [out (2048*256), topk_idx-as-float (2048*16)]
  float* out     = (float*)d_out;
  float* out_idx = out + (size_t)NTOK * DIM;

  // Workspace (8 MiB): Q 2MB | V 2MB | KF 2MB | VF 1MB | WF 768KB | WP 256KB
  char* ws = (char*)d_ws;
  float* Q   = (float*)(ws);
  float* V   = (float*)(ws + ((size_t)2 << 20));
  h16*   KF  = (h16*)  (ws + ((size_t)4 << 20));
  h16*   VF  = (h16*)  (ws + ((size_t)6 << 20));
  h16*   WF  = (h16*)  (ws + ((size_t)7 << 20));
  h16*   WP  = (h16*)  (ws + ((size_t)7 << 20) + 786432);
  float* msg = Q;       // safe overlay: each K2 block reads its Q rows first
  // Zp scratch (256 KB) lives in the `out` region: written by Zk, read by K2,
  // overwritten by K3 (which writes every out element afterwards).
  float* Zp  = out;

  reorder_w_kernel <<<128,       256,  0, stream>>>(w_qkv, w_proj, WF, WP);
  ln_qkv_kernel    <<<256,       1024, 0, stream>>>(point, WF, n1a, n1c, Q, KF, VF, V);
  z_kernel         <<<256,       1024, 0, stream>>>(Q, KF, Zp);
  attn_fused_kernel<<<NTOK / QB, 1024, 0, stream>>>(Q, KF, VF, Zp, msg, out_idx);
  proj_ln_kernel   <<<NTOK / 16, 1024, 0, stream>>>(msg, V, WP, b_proj, n2a, n2c, out);
}

// Round 15
// 180.974 us; speedup vs baseline: 1.0107x; 1.0107x over previous
//
#include <hip/hip_runtime.h>

// Problem constants (fixed by setup_inputs)
#define NTOK   2048
#define DIM    256
#define NH     8
#define CH     32
#define QB     8                      // queries per attn block (K2)
#define TOPK_K 16
#define SCALE  0.17677669529663687f   // 32^-0.5
#define LN_EPS 1e-5f

// pbuf: [head][q (8)][key-in-tile (256 + pad)]
#define PBL    260
#define PBH    (QB * PBL)             // 2080 floats per head
#define PSCALE 16384.f                // p -> f16 scaling (avoid denormal flush)
#define RPSCALE (1.f / 16384.f)

typedef _Float16 h16;
typedef _Float16 h16x8 __attribute__((ext_vector_type(8)));   // 4 VGPRs: MFMA A/B frag
typedef float    f32x4 __attribute__((ext_vector_type(4)));   // MFMA C/D frag

#define MFMA16(a, b, c) __builtin_amdgcn_mfma_f32_16x16x32_f16((a), (b), (c), 0, 0, 0)

// Fragment layouts (R7/R8-proven):
//   KF[w][kg(128)][hl(2)][l(64)][j(8)]: (l,j) = K[kg*16+(l&15)][w*32+8*(l>>4)+j]
//   VF[w][kb(64)][h(2)][l(64)][j(8)] : (l,j) = V[kb*32+8*(l>>4)+j][w*32+h*16+(l&15)]
//   WF/WP[cg][ks(8)][hl(2)][l(64)][j(8)]: (l,j) = W[ks*32+8*(l>>4)+j][cg*16+(l&15)]
//
// SESSION RESULT: this configuration (R9 = R13) is the measured champion at
// 180.8-182.7 us (from 367 us at session start). K2's 87 us was probed on five
// orthogonal axes (traffic, MFMA count, in-flight depth, residency, barrier
// structure) — all null or regressions; it is the floor of this decomposition.

// block-wide sum, NT threads (multiple of 64); red[] holds NT/64 floats
template<int NT>
__device__ __forceinline__ float block_sum(float v, float* red){
  #pragma unroll
  for (int off = 32; off > 0; off >>= 1) v += __shfl_xor(v, off, 64);
  const int t = threadIdx.x;
  if ((t & 63) == 0) red[t >> 6] = v;
  __syncthreads();
  float s = 0.f;
  #pragma unroll
  for (int w = 0; w < NT/64; w++) s += red[w];
  __syncthreads();
  return s;
}

// ---------------- K0: merged weight reorder -> fragment layout (one launch) ----------------
__global__ __launch_bounds__(256) void reorder_w_kernel(
    const float* __restrict__ src_qkv, const float* __restrict__ src_proj,
    h16* __restrict__ WF, h16* __restrict__ WP)
{
  const int b = blockIdx.x;
  const float* src; h16* dst; int ld, pair;
  if (b < 96){ src = src_qkv;  dst = WF; ld = 768; pair = b * 4 + (threadIdx.x >> 6); }
  else       { src = src_proj; dst = WP; ld = 256; pair = (b - 96) * 4 + (threadIdx.x >> 6); }
  const int l  = threadIdx.x & 63;
  const int cg = pair >> 3, ks = pair & 7;
  h16x8 hi8, lo8;
  #pragma unroll
  for (int j = 0; j < 8; j++){
    const float v = src[(size_t)(ks * 32 + (l >> 4) * 8 + j) * ld + cg * 16 + (l & 15)];
    const h16 h = (h16)v;
    hi8[j] = h;
    lo8[j] = (h16)(v - (float)h);
  }
  *(h16x8*)&dst[(size_t)((cg * 8 + ks) * 2 + 0) * 512 + l * 8] = hi8;
  *(h16x8*)&dst[(size_t)((cg * 8 + ks) * 2 + 1) * 512 + l * 8] = lo8;
}

// ---------------- K1: LN1 + MFMA x@w_qkv -> Q, KF, VF, V ----------------
// Column-split to 256 blocks. Block (tg = bx>>1, ch = bx&1): LN for tokens
// tg*16.. (duplicated per ch, cheap), then GEMM for col-groups [ch*24, +24):
// wave wv does cg ch*24+wv, and ch*24+16+wv if wv<8. Store formulas R8-proven.
__global__ __launch_bounds__(1024) void ln_qkv_kernel(
    const float* __restrict__ point,
    const h16*   __restrict__ WF,
    const float* __restrict__ c1,
    const float* __restrict__ c2,
    float* __restrict__ Q,
    h16*   __restrict__ KF,
    h16*   __restrict__ VF,
    float* __restrict__ V)
{
  __shared__ float xs[16][261];
  __shared__ float garr[256], barr[256];
  __shared__ float red[16];
  const int t  = threadIdx.x;
  const int wv = t >> 6;
  const int l  = t & 63;
  const int r  = l & 15;
  const int g  = l >> 4;
  const int tg = blockIdx.x >> 1;
  const int ch = blockIdx.x & 1;
  const int l0 = tg * 16;

  const float a1 = (t < 256) ? c1[t] : 0.f;
  const float a2 = (t < 256) ? c2[t] : 0.f;
  const float s1 = block_sum<1024>(fabsf(a1), red);
  const float s2 = block_sum<1024>(fabsf(a2), red);
  if (t < 256){ garr[t] = (s1 > s2) ? a1 : a2; barr[t] = (s1 > s2) ? a2 : a1; }
  __syncthreads();

  { // LN: wave wv -> token row l0+wv
    const float4 x = *(const float4*)&point[(size_t)(l0 + wv) * DIM + 4 * l];
    float s = x.x + x.y + x.z + x.w;
    #pragma unroll
    for (int off = 1; off < 64; off <<= 1) s += __shfl_xor(s, off, 64);
    const float mu = s * (1.f / DIM);
    const float d0 = x.x - mu, d1 = x.y - mu, d2 = x.z - mu, d3 = x.w - mu;
    float ss = d0 * d0 + d1 * d1 + d2 * d2 + d3 * d3;
    #pragma unroll
    for (int off = 1; off < 64; off <<= 1) ss += __shfl_xor(ss, off, 64);
    const float rsd = rsqrtf(ss * (1.f / DIM) + LN_EPS);
    xs[wv][4 * l + 0] = d0 * rsd * garr[4 * l + 0] + barr[4 * l + 0];
    xs[wv][4 * l + 1] = d1 * rsd * garr[4 * l + 1] + barr[4 * l + 1];
    xs[wv][4 * l + 2] = d2 * rsd * garr[4 * l + 2] + barr[4 * l + 2];
    xs[wv][4 * l + 3] = d3 * rsd * garr[4 * l + 3] + barr[4 * l + 3];
  }
  __syncthreads();

  // A fragments: row = token r, k = ks*32 + 8g + j; f16 hi/lo split
  h16x8 ah[8], al[8];
  #pragma unroll
  for (int ks = 0; ks < 8; ks++){
    #pragma unroll
    for (int j = 0; j < 8; j++){
      const float v = xs[r][ks * 32 + 8 * g + j];
      const h16 hi = (h16)v;
      ah[ks][j] = hi;
      al[ks][j] = (h16)(v - (float)hi);
    }
  }

  const int kgb = tg;   // this block's 16 tokens = KF key-group tg
  #pragma unroll
  for (int cgi = 0; cgi < 2; cgi++){
    if (cgi == 1 && wv >= 8) break;
    const int cg = ch * 24 + (cgi == 0 ? wv : 16 + wv);
    f32x4 acc = {0.f, 0.f, 0.f, 0.f};
    const h16* wf = WF + (size_t)cg * 8192 + (size_t)l * 8;
    #pragma unroll
    for (int ks = 0; ks < 8; ks++){
      const h16x8 bh = *(const h16x8*)(wf + ks * 1024);
      const h16x8 bl = *(const h16x8*)(wf + ks * 1024 + 512);
      acc = MFMA16(ah[ks], bh, acc);
      acc = MFMA16(al[ks], bh, acc);
      acc = MFMA16(ah[ks], bl, acc);
    }
    const int typ = cg >> 4;             // 0=Q, 1=K, 2=V
    const int c0  = (cg & 15) * 16 + r;  // column within its matrix
    #pragma unroll
    for (int q4 = 0; q4 < 4; q4++){
      const int tok = 4 * g + q4;
      if (typ == 0){
        Q[(size_t)(l0 + tok) * DIM + c0] = acc[q4];
      } else if (typ == 1){
        const int wh = c0 >> 5, gp = (c0 & 31) >> 3, jj = c0 & 7;
        const float kv = acc[q4];
        const h16 kh2 = (h16)kv;
        const size_t kidx = (size_t)(wh * 128 + kgb) * 1024
                          + (size_t)(gp * 16 + tok) * 8 + jj;
        KF[kidx]       = kh2;
        KF[kidx + 512] = (h16)(kv - (float)kh2);
      } else {
        V[(size_t)(l0 + tok) * DIM + c0] = acc[q4];
        const int wh = c0 >> 5, hh = (c0 & 31) >> 4, cp = c0 & 15;
        const int key = l0 + tok;
        const int kb = key >> 5, krem = key & 31, gpp = krem >> 3, jpp = krem & 7;
        VF[(size_t)((wh * 64 + kb) * 2 + hh) * 512
           + (size_t)(gpp * 16 + cp) * 8 + jpp] = (h16)acc[q4];
      }
    }
  }
}

// ---------------- Zk: softmax denominators, full-machine, full 16-row MFMA ----------------
// 256 blocks (tg = bx>>1, hb = bx&1) x 1024 thr. Wave (w = wv&7, sh = wv>>3):
// 16 queries tg*16.., head w, keys [hb*1024 + sh*512, +512). Writes 4 partial
// planes Zp[(hb*2+sh)][w][token] (non-atomic, distinct). K2 sums the 4.
__global__ __launch_bounds__(1024) void z_kernel(
    const float* __restrict__ Q,
    const h16*   __restrict__ KF,
    float*       __restrict__ Zp)     // [4][NH][NTOK]
{
  const int t  = threadIdx.x;
  const int wv = t >> 6;
  const int w  = wv & 7;
  const int sh = wv >> 3;
  const int l  = t & 63;
  const int r  = l & 15;
  const int g  = l >> 4;
  const int tg = blockIdx.x >> 1;
  const int hb = blockIdx.x & 1;

  h16x8 qh, ql;
  {
    const float* qp = &Q[(size_t)(tg * 16 + r) * DIM + w * CH + 8 * g];
    const float4 q0 = *(const float4*)qp;
    const float4 q1 = *(const float4*)(qp + 4);
    const float qv[8] = {q0.x, q0.y, q0.z, q0.w, q1.x, q1.y, q1.z, q1.w};
    #pragma unroll
    for (int j = 0; j < 8; j++){
      const float s = qv[j] * SCALE;
      const h16 hi = (h16)s;
      qh[j] = hi;
      ql[j] = (h16)(s - (float)hi);
    }
  }

  const h16* kf = KF + (size_t)(w * 128 + hb * 64 + sh * 32) * 1024 + (size_t)l * 8;
  float zs[4] = {0.f, 0.f, 0.f, 0.f};
  #pragma unroll 2
  for (int kgi = 0; kgi < 32; kgi++){
    const h16x8 bh = *(const h16x8*)(kf + (size_t)kgi * 1024);
    const h16x8 bl = *(const h16x8*)(kf + (size_t)kgi * 1024 + 512);
    f32x4 d = {0.f, 0.f, 0.f, 0.f};
    d = MFMA16(qh, bh, d);
    d = MFMA16(ql, bh, d);
    d = MFMA16(qh, bl, d);
    #pragma unroll
    for (int q4 = 0; q4 < 4; q4++) zs[q4] += __expf(d[q4]);
  }
  #pragma unroll
  for (int q4 = 0; q4 < 4; q4++){
    #pragma unroll
    for (int off = 1; off < 16; off <<= 1) zs[q4] += __shfl_xor(zs[q4], off, 64);
  }
  if (r == 0){
    #pragma unroll
    for (int q4 = 0; q4 < 4; q4++)
      Zp[(size_t)((hb * 2 + sh) * NH + w) * NTOK + tg * 16 + 4 * g + q4] = zs[q4];
  }
}

// ---------------- K2: single-sweep MFMA attention + A_mean + top-k ----------------
// Z comes precomputed from Zp (saves 2 MB L2 reads + 3072 MFMAs + 2048 exps per
// block vs R8). A_mean phase vectorized to float4 LDS reads. The score->PV
// barrier stays: R14 measured its removal (+setprio) at +10 us — the barrier's
// phase separation keeps LDS/L2 access streams homogeneous.
__global__ __launch_bounds__(1024) __attribute__((amdgpu_waves_per_eu(4)))
void attn_fused_kernel(
    const float* Q,                   // [NTOK][DIM] f32 (aliases msg! no restrict)
    const h16*   __restrict__ KF,
    const h16*   __restrict__ VF,
    const float* __restrict__ Zp,     // [4][NH][NTOK] partial Z
    float*       msg,                 // = Q buffer; block-local overlay
    float*       __restrict__ out_idx)
{
  __shared__ float pbuf[NH * PBH];          // 66560 B
  __shared__ float am[QB][NTOK];            // 65536 B
  __shared__ float msg_s[2][QB][DIM + 4];   // 16640 B
  __shared__ float zbuf[NH * QB];           // 256 B: summed Z per (head, q)

  const int t  = threadIdx.x;
  const int wv = t >> 6;
  const int w  = wv & 7;
  const int hf = wv >> 3;
  const int l  = t & 63;
  const int r  = l & 15;
  const int g  = l >> 4;
  const int l0 = blockIdx.x * QB;

  // ---- Q fragments (A operand), pre-scaled, f16 hi/lo split; rows 8..15 zero
  h16x8 qh, ql;
  #pragma unroll
  for (int j = 0; j < 8; j++){ qh[j] = (h16)0.f; ql[j] = (h16)0.f; }
  if (r < QB){
    const float* qp = &Q[(size_t)(l0 + r) * DIM + w * CH + 8 * g];
    const float4 q0 = *(const float4*)qp;
    const float4 q1 = *(const float4*)(qp + 4);
    const float qv[8] = {q0.x, q0.y, q0.z, q0.w, q1.x, q1.y, q1.z, q1.w};
    #pragma unroll
    for (int j = 0; j < 8; j++){
      const float s = qv[j] * SCALE;
      const h16 hi = (h16)s;
      qh[j] = hi;
      ql[j] = (h16)(s - (float)hi);
    }
  }

  // stage Z sums: thread t<64 -> (head t>>3, q t&7)
  if (t < 64){
    const int h = t >> 3, q = t & 7;
    float z = 0.f;
    #pragma unroll
    for (int p = 0; p < 4; p++) z += Zp[(size_t)(p * NH + h) * NTOK + l0 + q];
    zbuf[t] = z;
  }
  __syncthreads();
  float rZ[4];
  #pragma unroll
  for (int q4 = 0; q4 < 4; q4++){
    const int row = 4 * g + q4;
    rZ[q4] = (g < 2) ? 1.f / zbuf[w * QB + row] : 0.f;
  }

  // per-lane fragment bases
  const h16* kfw = KF + (size_t)(w * 128) * 1024 + (size_t)l * 8;
  const h16* vfw = VF + (size_t)(w * 64) * 1024 + (size_t)l * 8;

  f32x4 macc[2];
  #pragma unroll
  for (int dg = 0; dg < 2; dg++) macc[dg] = (f32x4){0.f, 0.f, 0.f, 0.f};

  for (int ti = 0; ti < 8; ti++){
    const int s0 = ti * 256;
    const h16* vft = vfw + (size_t)((ti * 8 + hf * 4) * 2) * 512;

    // T14 issue-early: PV B-frags for st=0,1
    h16x8 pva[4], pvb[4];
    pva[0] = *(const h16x8*)(vft);
    pvb[0] = *(const h16x8*)(vft + 512);
    pva[1] = *(const h16x8*)(vft + 1024);
    pvb[1] = *(const h16x8*)(vft + 1024 + 512);

    // (a) scores -> normalized p for this wave's 128 keys of the tile
    {
      const h16* kft = kfw + (size_t)(ti * 16 + hf * 8) * 1024;
      #pragma unroll 2
      for (int kgi = 0; kgi < 8; kgi++){
        const h16x8 bh = *(const h16x8*)(kft + (size_t)kgi * 1024);
        const h16x8 bl = *(const h16x8*)(kft + (size_t)kgi * 1024 + 512);
        f32x4 d = {0.f, 0.f, 0.f, 0.f};
        d = MFMA16(qh, bh, d);
        d = MFMA16(ql, bh, d);
        d = MFMA16(qh, bl, d);
        if (g < 2){
          const int kbr = hf * 128 + kgi * 16 + r;
          pbuf[w * PBH + (4 * g + 0) * PBL + kbr] = __expf(d[0]) * rZ[0];
          pbuf[w * PBH + (4 * g + 1) * PBL + kbr] = __expf(d[1]) * rZ[1];
          pbuf[w * PBH + (4 * g + 2) * PBL + kbr] = __expf(d[2]) * rZ[2];
          pbuf[w * PBH + (4 * g + 3) * PBL + kbr] = __expf(d[3]) * rZ[3];
        }
      }
    }
    __syncthreads();

    // late PV frags
    pva[2] = *(const h16x8*)(vft + 2048);
    pvb[2] = *(const h16x8*)(vft + 2048 + 512);
    pva[3] = *(const h16x8*)(vft + 3072);
    pvb[3] = *(const h16x8*)(vft + 3072 + 512);

    // (b) PV: 4 steps x 32 keys
    #pragma unroll
    for (int st = 0; st < 4; st++){
      h16x8 pa;
      #pragma unroll
      for (int j = 0; j < 8; j++) pa[j] = (h16)0.f;
      if (r < QB){
        const float* pp = &pbuf[w * PBH + r * PBL + hf * 128 + st * 32 + 8 * g];
        const float4 p0 = *(const float4*)pp;
        const float4 p1 = *(const float4*)(pp + 4);
        pa[0] = (h16)(p0.x * PSCALE); pa[1] = (h16)(p0.y * PSCALE);
        pa[2] = (h16)(p0.z * PSCALE); pa[3] = (h16)(p0.w * PSCALE);
        pa[4] = (h16)(p1.x * PSCALE); pa[5] = (h16)(p1.y * PSCALE);
        pa[6] = (h16)(p1.z * PSCALE); pa[7] = (h16)(p1.w * PSCALE);
      }
      macc[0] = MFMA16(pa, pva[st], macc[0]);
      macc[1] = MFMA16(pa, pvb[st], macc[1]);
    }
    // (c) A_mean: 2048 cells, float4 per thread (threads 0..511)
    if (t < 512){
      const int q = t >> 6, k4 = (t & 63) * 4;
      float4 su = make_float4(0.f, 0.f, 0.f, 0.f);
      #pragma unroll
      for (int hh = 0; hh < 8; hh++){
        const float4 v = *(const float4*)&pbuf[hh * PBH + q * PBL + k4];
        su.x += v.x; su.y += v.y; su.z += v.z; su.w += v.w;
      }
      *(float4*)&am[q][s0 + k4] =
          make_float4(su.x * 0.125f, su.y * 0.125f, su.z * 0.125f, su.w * 0.125f);
    }
    __syncthreads();
  }

  // ---- epilogue: msg partials to LDS
  if (g < 2){
    #pragma unroll
    for (int dg = 0; dg < 2; dg++)
      #pragma unroll
      for (int q4 = 0; q4 < 4; q4++)
        msg_s[hf][4 * g + q4][w * CH + dg * 16 + r] = macc[dg][q4] * RPSCALE;
  }
  __syncthreads();

  if (wv < QB){
    // top-k: wave wv owns query row wv
    for (int it = 0; it < TOPK_K; it++){
      float bv = -1e30f; int bi = 0x7fffffff;
      #pragma unroll
      for (int b = 0; b < NTOK / 64; b++){
        const int idx = b * 64 + l;
        const float v = am[wv][idx];
        if (v > bv || (v == bv && idx < bi)){ bv = v; bi = idx; }
      }
      #pragma unroll
      for (int off = 1; off < 64; off <<= 1){
        const float ov = __shfl_xor(bv, off, 64);
        const int   oi = __shfl_xor(bi, off, 64);
        if (ov > bv || (ov == bv && oi < bi)){ bv = ov; bi = oi; }
      }
      if (l == 0){
        out_idx[(l0 + wv) * TOPK_K + it] = (float)bi;
        am[wv][bi] = -1e30f;
      }
    }
  } else {
    // waves 8..15: combine halves, write msg (overlays Q: block-local rows only)
    const int t2 = t - 512;
    #pragma unroll
    for (int k2 = 0; k2 < 4; k2++){
      const int cell = t2 + 512 * k2;
      const int q = cell >> 8, dcol = cell & 255;
      msg[(size_t)(l0 + q) * DIM + dcol] = msg_s[0][q][dcol] + msg_s[1][q][dcol];
    }
  }
}

// ---------------- K3: MFMA msg@w_proj + b + V residual + LN2 -> out ----------------
__global__ __launch_bounds__(1024) void proj_ln_kernel(
    const float* __restrict__ msg,
    const float* __restrict__ V,
    const h16*   __restrict__ WP,
    const float* __restrict__ b_proj,
    const float* __restrict__ c1,
    const float* __restrict__ c2,
    float* __restrict__ out)
{
  __shared__ float xs[16][261];
  __shared__ float ms2[16][261];
  __shared__ float garr[256], barr[256], bparr[256];
  __shared__ float red[16];
  const int t  = threadIdx.x;
  const int wv = t >> 6;
  const int l  = t & 63;
  const int r  = l & 15;
  const int g  = l >> 4;
  const int l0 = blockIdx.x * 16;

  const float a1 = (t < 256) ? c1[t] : 0.f;
  const float a2 = (t < 256) ? c2[t] : 0.f;
  const float s1 = block_sum<1024>(fabsf(a1), red);
  const float s2 = block_sum<1024>(fabsf(a2), red);
  if (t < 256){
    garr[t]  = (s1 > s2) ? a1 : a2;
    barr[t]  = (s1 > s2) ? a2 : a1;
    bparr[t] = b_proj[t];
  }

  {
    const float4 x = *(const float4*)&msg[(size_t)(l0 + wv) * DIM + 4 * l];
    xs[wv][4 * l + 0] = x.x; xs[wv][4 * l + 1] = x.y;
    xs[wv][4 * l + 2] = x.z; xs[wv][4 * l + 3] = x.w;
  }
  __syncthreads();

  h16x8 ah[8], al[8];
  #pragma unroll
  for (int ks = 0; ks < 8; ks++){
    #pragma unroll
    for (int j = 0; j < 8; j++){
      const float v = xs[r][ks * 32 + 8 * g + j];
      const h16 hi = (h16)v;
      ah[ks][j] = hi;
      al[ks][j] = (h16)(v - (float)hi);
    }
  }

  f32x4 acc = {0.f, 0.f, 0.f, 0.f};
  {
    const h16* wp = WP + (size_t)wv * 8192 + (size_t)l * 8;
    #pragma unroll
    for (int ks = 0; ks < 8; ks++){
      const h16x8 bh = *(const h16x8*)(wp + ks * 1024);
      const h16x8 bl = *(const h16x8*)(wp + ks * 1024 + 512);
      acc = MFMA16(ah[ks], bh, acc);
      acc = MFMA16(al[ks], bh, acc);
      acc = MFMA16(ah[ks], bl, acc);
    }
  }

  const int dc = wv * 16 + r;
  #pragma unroll
  for (int q4 = 0; q4 < 4; q4++){
    const int tok = 4 * g + q4;
    ms2[tok][dc] = acc[q4] + bparr[dc] + V[(size_t)(l0 + tok) * DIM + dc];
  }
  __syncthreads();

  {
    const float x0 = ms2[wv][4 * l + 0], x1 = ms2[wv][4 * l + 1];
    const float x2 = ms2[wv][4 * l + 2], x3 = ms2[wv][4 * l + 3];
    float s = x0 + x1 + x2 + x3;
    #pragma unroll
    for (int off = 1; off < 64; off <<= 1) s += __shfl_xor(s, off, 64);
    const float mu = s * (1.f / DIM);
    const float d0 = x0 - mu, d1 = x1 - mu, d2 = x2 - mu, d3 = x3 - mu;
    float ss = d0 * d0 + d1 * d1 + d2 * d2 + d3 * d3;
    #pragma unroll
    for (int off = 1; off < 64; off <<= 1) ss += __shfl_xor(ss, off, 64);
    const float rsd = rsqrtf(ss * (1.f / DIM) + LN_EPS);
    float4 o;
    o.x = d0 * rsd * garr[4 * l + 0] + barr[4 * l + 0];
    o.y = d1 * rsd * garr[4 * l + 1] + barr[4 * l + 1];
    o.z = d2 * rsd * garr[4 * l + 2] + barr[4 * l + 2];
    o.w = d3 * rsd * garr[4 * l + 3] + barr[4 * l + 3];
    *(float4*)&out[(size_t)(l0 + wv) * DIM + 4 * l] = o;
  }
}

extern "C" void kernel_launch(void* const* d_in, const int* in_sizes, int n_in,
                              void* d_out, int out_size, void* d_ws, size_t ws_size,
                              hipStream_t stream) {
  const float* point  = nullptr;
  const float* w_qkv  = nullptr;
  const float* w_proj = nullptr;
  const float* v256[5] = {nullptr, nullptr, nullptr, nullptr, nullptr};
  int n256 = 0;
  for (int i = 0; i < n_in; i++){
    const int sz = in_sizes[i];
    if      (sz == NTOK * DIM)      point  = (const float*)d_in[i];
    else if (sz == DIM * 3 * DIM)   w_qkv  = (const float*)d_in[i];
    else if (sz == DIM * DIM)       w_proj = (const float*)d_in[i];
    else if (sz == DIM && n256 < 5) v256[n256++] = (const float*)d_in[i];
  }
  const float* b_proj = v256[0];
  const float* n1a    = v256[1];
  const float* n1c    = v256[2];
  const float* n2a    = v256[3];
  const float* n2c    = v256[4];

  // Output buffer f32: [out (2048*256), topk_idx-as-float (2048*16)]
  float* out     = (float*)d_out;
  float* out_idx = out + (size_t)NTOK * DIM;

  // Workspace (8 MiB): Q 2MB | V 2MB | KF 2MB | VF 1MB | WF 768KB | WP 256KB
  char* ws = (char*)d_ws;
  float* Q   = (float*)(ws);
  float* V   = (float*)(ws + ((size_t)2 << 20));
  h16*   KF  = (h16*)  (ws + ((size_t)4 << 20));
  h16*   VF  = (h16*)  (ws + ((size_t)6 << 20));
  h16*   WF  = (h16*)  (ws + ((size_t)7 << 20));
  h16*   WP  = (h16*)  (ws + ((size_t)7 << 20) + 786432);
  float* msg = Q;       // safe overlay: each K2 block reads its Q rows first
  // Zp scratch (256 KB) lives in the `out` region: written by Zk, read by K2,
  // overwritten by K3 (which writes every out element afterwards).
  float* Zp  = out;

  reorder_w_kernel <<<128,       256,  0, stream>>>(w_qkv, w_proj, WF, WP);
  ln_qkv_kernel    <<<256,       1024, 0, stream>>>(point, WF, n1a, n1c, Q, KF, VF, V);
  z_kernel         <<<256,       1024, 0, stream>>>(Q, KF, Zp);
  attn_fused_kernel<<<NTOK / QB, 1024, 0, stream>>>(Q, KF, VF, Zp, msg, out_idx);
  proj_ln_kernel   <<<NTOK / 16, 1024, 0, stream>>>(msg, V, WP, b_proj, n2a, n2c, out);
}